// Round 9
// baseline (589.760 us; speedup 1.0000x reference)
//
#include <hip/hip_runtime.h>
#include <hip/hip_fp16.h>

// N_NODES=100000, N_EDGES=50000, NNZ=1600000, dims 128->128->16, fp32 I/O.
// Message path fp16, accumulate fp32. CSR build: LDS-only counting sort.
// F=128 aggregations: feature-sliced across XCDs (slice = blockIdx&7) so each
// gather table slice (1.6-3.2 MB) is L2-resident on one XCD. Layouts for
// xw16/ef16/h16 are slice-major: [8][rows][8 x half2].

#define N_EDGES_C 50000
#define F1 128
#define F2 16
#define CHUNK 4096
#define EBIN_SHIFT 7
#define NBIN_SHIFT 8
#define EBINS 391
#define NBINS 391
#define SLCN 800000               // half2 per slice for node-indexed tensors (100000*8)
#define SLCE 400000               // half2 per slice for edge-indexed tensors (50000*8)

// ---------------- CSR build ----------------

__global__ __launch_bounds__(256) void hist_chunk_kernel(
    const int* __restrict__ node_idx, const int* __restrict__ edge_idx,
    int* __restrict__ echunkcnt, int* __restrict__ nchunkcnt, int nnz) {
  __shared__ int ebc[EBINS], nbc[NBINS];
  const int t = threadIdx.x;
  for (int b = t; b < EBINS; b += 256) ebc[b] = 0;
  for (int b = t; b < NBINS; b += 256) nbc[b] = 0;
  __syncthreads();
  const int base = blockIdx.x * CHUNK;
  int end = base + CHUNK; if (end > nnz) end = nnz;
  for (int i = base + t; i < end; i += 256) {
    atomicAdd(&ebc[edge_idx[i] >> EBIN_SHIFT], 1);
    atomicAdd(&nbc[node_idx[i] >> NBIN_SHIFT], 1);
  }
  __syncthreads();
  const int nC = gridDim.x;
  for (int b = t; b < EBINS; b += 256) echunkcnt[b * nC + blockIdx.x] = ebc[b];
  for (int b = t; b < NBINS; b += 256) nchunkcnt[b * nC + blockIdx.x] = nbc[b];
}

__global__ __launch_bounds__(256) void cscan_p1_kernel(
    const int* __restrict__ ecc, const int* __restrict__ ncc,
    int* __restrict__ epart, int* __restrict__ npart,
    int Le, int Ln, int nbE) {
  __shared__ int red[256];
  const int t = threadIdx.x;
  const int b = blockIdx.x;
  const int* src; int L; int* dst; int bb;
  if (b < nbE) { src = ecc; L = Le; dst = epart; bb = b; }
  else         { src = ncc; L = Ln; dst = npart; bb = b - nbE; }
  int base = bb * 1024 + t * 4;
  int s = 0;
#pragma unroll
  for (int j = 0; j < 4; ++j) { int i = base + j; if (i < L) s += src[i]; }
  red[t] = s;
  __syncthreads();
  for (int d = 128; d > 0; d >>= 1) {
    if (t < d) red[t] += red[t + d];
    __syncthreads();
  }
  if (t == 0) dst[bb] = red[0];
}

__global__ __launch_bounds__(256) void cscan_p2_kernel(
    int* __restrict__ epart, int* __restrict__ npart,
    int* __restrict__ ebinbase, int* __restrict__ nbinbase,
    int nbE, int nbN, int nnz) {
  __shared__ int se[256], sn[256];
  const int t = threadIdx.x;
  se[t] = (t < nbE) ? epart[t] : 0;
  sn[t] = (t < nbN) ? npart[t] : 0;
  __syncthreads();
  for (int d = 1; d < 256; d <<= 1) {
    int ve = (t >= d) ? se[t - d] : 0;
    int vn = (t >= d) ? sn[t - d] : 0;
    __syncthreads();
    se[t] += ve; sn[t] += vn;
    __syncthreads();
  }
  if (t < nbE) epart[t] = (t > 0) ? se[t - 1] : 0;
  if (t < nbN) npart[t] = (t > 0) ? sn[t - 1] : 0;
  if (t == 0) { ebinbase[EBINS] = nnz; nbinbase[NBINS] = nnz; }
}

__global__ __launch_bounds__(256) void cscan_p3_kernel(
    const int* __restrict__ ecc, const int* __restrict__ ncc,
    const int* __restrict__ epart, const int* __restrict__ npart,
    int* __restrict__ erunoff, int* __restrict__ nrunoff,
    int* __restrict__ ebinbase, int* __restrict__ nbinbase,
    int Le, int Ln, int nbE, int nC) {
  __shared__ int red[256];
  const int t = threadIdx.x;
  const int b = blockIdx.x;
  const int* src; const int* part; int L; int* ro; int* bba; int bb;
  if (b < nbE) { src = ecc; part = epart; L = Le; ro = erunoff; bba = ebinbase; bb = b; }
  else         { src = ncc; part = npart; L = Ln; ro = nrunoff; bba = nbinbase; bb = b - nbE; }
  int base = bb * 1024 + t * 4;
  int v[4]; int s = 0;
#pragma unroll
  for (int j = 0; j < 4; ++j) { int i = base + j; v[j] = (i < L) ? src[i] : 0; s += v[j]; }
  red[t] = s;
  __syncthreads();
  for (int d = 1; d < 256; d <<= 1) {
    int x = (t >= d) ? red[t - d] : 0;
    __syncthreads();
    red[t] += x;
    __syncthreads();
  }
  int run = part[bb] + ((t > 0) ? red[t - 1] : 0);
#pragma unroll
  for (int j = 0; j < 4; ++j) {
    int i = base + j;
    if (i < L) {
      ro[i] = run;
      if (i % nC == 0) bba[i / nC] = run;
      run += v[j];
    }
  }
}

__global__ __launch_bounds__(256) void stage_kernel(
    const int* __restrict__ node_idx, const int* __restrict__ edge_idx,
    const int* __restrict__ erunoff, const int* __restrict__ nrunoff,
    int2* __restrict__ epairs, int2* __restrict__ npairs, int nnz) {
  __shared__ int ecur[EBINS], ncur[NBINS];
  const int t = threadIdx.x;
  const int nC = gridDim.x;
  for (int b = t; b < EBINS; b += 256) ecur[b] = erunoff[b * nC + blockIdx.x];
  for (int b = t; b < NBINS; b += 256) ncur[b] = nrunoff[b * nC + blockIdx.x];
  __syncthreads();
  const int base = blockIdx.x * CHUNK;
  int end = base + CHUNK; if (end > nnz) end = nnz;
  for (int i = base + t; i < end; i += 256) {
    int e = edge_idx[i];
    int n = node_idx[i];
    int p = atomicAdd(&ecur[e >> EBIN_SHIFT], 1);
    epairs[p] = make_int2(e, n);
    int q = atomicAdd(&ncur[n >> NBIN_SHIFT], 1);
    npairs[q] = make_int2(n, e);
  }
}

__global__ __launch_bounds__(256) void bin_scatter_kernel(
    const int2* __restrict__ epairs, const int2* __restrict__ npairs,
    const int* __restrict__ ebinbase, const int* __restrict__ nbinbase,
    int* __restrict__ eoff, int* __restrict__ noff,
    int* __restrict__ enbr, int* __restrict__ nnbr,
    int n_edges, int n_nodes) {
  __shared__ int cnt[256];
  __shared__ int scn[256];
  const int bid = blockIdx.x;
  const int t = threadIdx.x;
  if (bid < EBINS) {
    const int e0 = bid << EBIN_SHIFT;
    const int ne = min(1 << EBIN_SHIFT, n_edges - e0);
    const int beg = ebinbase[bid], end = ebinbase[bid + 1];
    if (t < 128) cnt[t] = 0;
    __syncthreads();
    for (int j = beg + t; j < end; j += 256) atomicAdd(&cnt[epairs[j].x & 127], 1);
    __syncthreads();
    if (t < 128) scn[t] = cnt[t];
    __syncthreads();
    for (int d = 1; d < 128; d <<= 1) {
      int x = 0;
      if (t < 128 && t >= d) x = scn[t - d];
      __syncthreads();
      if (t < 128) scn[t] += x;
      __syncthreads();
    }
    int pos0 = 0;
    if (t < 128) {
      int excl = (t > 0) ? scn[t - 1] : 0;
      pos0 = beg + excl;
      if (t < ne) eoff[e0 + t] = pos0;
    }
    __syncthreads();
    if (t < 128) scn[t] = pos0;
    __syncthreads();
    for (int j = beg + t; j < end; j += 256) {
      int2 p = epairs[j];
      int pos = atomicAdd(&scn[p.x & 127], 1);
      enbr[pos] = p.y;
    }
    if (bid == EBINS - 1 && t == 0) eoff[n_edges] = end;
  } else {
    const int b = bid - EBINS;
    const int n0 = b << NBIN_SHIFT;
    const int nn = min(1 << NBIN_SHIFT, n_nodes - n0);
    const int beg = nbinbase[b], end = nbinbase[b + 1];
    cnt[t] = 0;
    __syncthreads();
    for (int j = beg + t; j < end; j += 256) atomicAdd(&cnt[npairs[j].x & 255], 1);
    __syncthreads();
    scn[t] = cnt[t];
    __syncthreads();
    for (int d = 1; d < 256; d <<= 1) {
      int x = (t >= d) ? scn[t - d] : 0;
      __syncthreads();
      scn[t] += x;
      __syncthreads();
    }
    int excl = (t > 0) ? scn[t - 1] : 0;
    int pos0 = beg + excl;
    if (t < nn) noff[n0 + t] = pos0;
    __syncthreads();
    scn[t] = pos0;
    __syncthreads();
    for (int j = beg + t; j < end; j += 256) {
      int2 p = npairs[j];
      int pos = atomicAdd(&scn[p.x & 255], 1);
      nnbr[pos] = p.y;
    }
    if (bid == EBINS + NBINS - 1 && t == 0) noff[n_nodes] = end;
  }
}

// ---------------- GEMM1: xw16_s[8][M][8h2] = x[M x 128] @ W1, slice-major fp16 out ----

__global__ __launch_bounds__(256) void gemm1_kernel(
    const float* __restrict__ A, const float* __restrict__ B,
    __half2* __restrict__ C16S, int M) {
  __shared__ float xs[128][36];
  __shared__ float wsh[32][128];

  const int t = threadIdx.x;
  const int tx = t & 15;
  const int ty = t >> 4;
  const int bm = blockIdx.x * 128;

  float acc[8][8];
#pragma unroll
  for (int i = 0; i < 8; ++i)
#pragma unroll
    for (int j = 0; j < 8; ++j) acc[i][j] = 0.f;

  for (int kt = 0; kt < 4; ++kt) {
#pragma unroll
    for (int i = 0; i < 4; ++i) {
      int lin = i * 256 + t;
      int row = lin >> 3;
      int c4 = lin & 7;
      int grow = bm + row;
      float4 v = make_float4(0.f, 0.f, 0.f, 0.f);
      if (grow < M) v = *(const float4*)(A + (size_t)grow * 128 + kt * 32 + c4 * 4);
      *(float4*)&xs[row][c4 * 4] = v;
    }
#pragma unroll
    for (int i = 0; i < 4; ++i) {
      int lin = i * 256 + t;
      int k = lin >> 5;
      int c4 = lin & 31;
      *(float4*)&wsh[k][c4 * 4] = *(const float4*)(B + (size_t)(kt * 32 + k) * 128 + c4 * 4);
    }
    __syncthreads();

#pragma unroll 4
    for (int k = 0; k < 32; ++k) {
      float a[8], b[8];
#pragma unroll
      for (int j = 0; j < 4; ++j) {
        a[j]     = xs[ty * 4 + j][k];
        a[4 + j] = xs[ty * 4 + 64 + j][k];
      }
      float4 b0 = *(const float4*)&wsh[k][tx * 4];
      float4 b1 = *(const float4*)&wsh[k][tx * 4 + 64];
      b[0] = b0.x; b[1] = b0.y; b[2] = b0.z; b[3] = b0.w;
      b[4] = b1.x; b[5] = b1.y; b[6] = b1.z; b[7] = b1.w;
#pragma unroll
      for (int i = 0; i < 8; ++i)
#pragma unroll
        for (int j = 0; j < 8; ++j) acc[i][j] = fmaf(a[i], b[j], acc[i][j]);
    }
    __syncthreads();
  }

  // slice-major store: half2 col c -> C16S[(c>>3)*SLCN + row*8 + (c&7)]
#pragma unroll
  for (int i = 0; i < 8; ++i) {
    int row = (i < 4) ? (ty * 4 + i) : (ty * 4 + 64 + (i - 4));
    int grow = bm + row;
    if (grow < M) {
      int cA = tx * 2;        // half2 cols cA, cA+1
      int cB = 32 + tx * 2;   // half2 cols cB, cB+1
      C16S[(size_t)(cA >> 3) * SLCN + (size_t)grow * 8 + (cA & 7)] =
          __floats2half2_rn(acc[i][0], acc[i][1]);
      C16S[(size_t)((cA + 1) >> 3) * SLCN + (size_t)grow * 8 + ((cA + 1) & 7)] =
          __floats2half2_rn(acc[i][2], acc[i][3]);
      C16S[(size_t)(cB >> 3) * SLCN + (size_t)grow * 8 + (cB & 7)] =
          __floats2half2_rn(acc[i][4], acc[i][5]);
      C16S[(size_t)((cB + 1) >> 3) * SLCN + (size_t)grow * 8 + ((cB + 1) & 7)] =
          __floats2half2_rn(acc[i][6], acc[i][7]);
    }
  }
}

// ---------------- F=128 aggregation, XCD-sliced ----------------
// slice = blockIdx&7 (one table slice per XCD); wave = one segment;
// lane = (g = gather slot 0-7, f = half2 feature 0-7); x2 unroll = 16 nbrs in flight.

__global__ __launch_bounds__(256) void edge_agg128_kernel(
    const __half2* __restrict__ featS,   // xw16_s [8][SLCN]
    const int* __restrict__ nbr, const int* __restrict__ off,
    __half2* __restrict__ outS, int nseg) {       // ef16_s [8][SLCE]
  const int slice = blockIdx.x & 7;
  const int seg = (blockIdx.x >> 3) * 4 + (threadIdx.x >> 6);
  if (seg >= nseg) return;
  const int lane = threadIdx.x & 63;
  const int g = lane >> 3, f = lane & 7;
  const __half2* tab = featS + (size_t)slice * SLCN;
  int beg = off[seg], end = off[seg + 1];
  float sx0 = 0.f, sy0 = 0.f, sx1 = 0.f, sy1 = 0.f;
  int k = beg + g;
  for (; k + 8 < end; k += 16) {
    int n0 = nbr[k];
    int n1 = nbr[k + 8];
    float2 v0 = __half22float2(tab[(size_t)n0 * 8 + f]);
    float2 v1 = __half22float2(tab[(size_t)n1 * 8 + f]);
    sx0 += v0.x; sy0 += v0.y; sx1 += v1.x; sy1 += v1.y;
  }
  if (k < end) {
    float2 v = __half22float2(tab[(size_t)nbr[k] * 8 + f]);
    sx0 += v.x; sy0 += v.y;
  }
  float sx = sx0 + sx1, sy = sy0 + sy1;
#pragma unroll
  for (int d = 8; d < 64; d <<= 1) {
    sx += __shfl_xor(sx, d, 64);
    sy += __shfl_xor(sy, d, 64);
  }
  if (g == 0) {
    float inv = (end > beg) ? 1.f / (float)(end - beg) : 0.f;
    outS[(size_t)slice * SLCE + (size_t)seg * 8 + f] = __floats2half2_rn(sx * inv, sy * inv);
  }
}

__global__ __launch_bounds__(256) void node_agg128_kernel(
    const __half2* __restrict__ featS,   // ef16_s [8][SLCE]
    const int* __restrict__ nbr, const int* __restrict__ off,
    const float* __restrict__ bias,
    __half2* __restrict__ outS, int nseg) {       // h16_s [8][SLCN]
  const int slice = blockIdx.x & 7;
  const int seg = (blockIdx.x >> 3) * 4 + (threadIdx.x >> 6);
  if (seg >= nseg) return;
  const int lane = threadIdx.x & 63;
  const int g = lane >> 3, f = lane & 7;
  const __half2* tab = featS + (size_t)slice * SLCE;
  int beg = off[seg], end = off[seg + 1];
  float sx0 = 0.f, sy0 = 0.f, sx1 = 0.f, sy1 = 0.f;
  int k = beg + g;
  for (; k + 8 < end; k += 16) {
    int e0 = nbr[k];
    int e1 = nbr[k + 8];
    float2 v0 = __half22float2(tab[(size_t)e0 * 8 + f]);
    float2 v1 = __half22float2(tab[(size_t)e1 * 8 + f]);
    sx0 += v0.x; sy0 += v0.y; sx1 += v1.x; sy1 += v1.y;
  }
  if (k < end) {
    float2 v = __half22float2(tab[(size_t)nbr[k] * 8 + f]);
    sx0 += v.x; sy0 += v.y;
  }
  float sx = sx0 + sx1, sy = sy0 + sy1;
#pragma unroll
  for (int d = 8; d < 64; d <<= 1) {
    sx += __shfl_xor(sx, d, 64);
    sy += __shfl_xor(sy, d, 64);
  }
  if (g == 0) {
    float inv = (end > beg) ? 1.f / (float)(end - beg) : 0.f;
    float2 b = ((const float2*)bias)[slice * 8 + f];
    float hx = fmaxf(sx * inv + b.x, 0.f);
    float hy = fmaxf(sy * inv + b.y, 0.f);
    outS[(size_t)slice * SLCN + (size_t)seg * 8 + f] = __floats2half2_rn(hx, hy);
  }
}

// ---------------- GEMM2: hw2_16[M x 16] (fp16) = h16_s @ W2[128 x 16] ----------------

__global__ __launch_bounds__(256) void gemm2_kernel(
    const __half2* __restrict__ H16S, const float* __restrict__ W2,
    __half2* __restrict__ O16, int M) {
  __shared__ float ws2[128 * 16];
  const int t = threadIdx.x;
#pragma unroll
  for (int i = 0; i < 8; ++i) ws2[i * 256 + t] = W2[i * 256 + t];
  __syncthreads();

  int r0 = blockIdx.x * 512 + t;
  int r1 = r0 + 256;
  bool v0 = r0 < M, v1 = r1 < M;

  float4 acc0[4], acc1[4];
#pragma unroll
  for (int q = 0; q < 4; ++q) {
    acc0[q] = make_float4(0.f, 0.f, 0.f, 0.f);
    acc1[q] = make_float4(0.f, 0.f, 0.f, 0.f);
  }

  for (int s = 0; s < 8; ++s) {
    // 8 half2 (32B) per row per slice, coalesced across threads
    __half2 h0v[8], h1v[8];
#pragma unroll
    for (int u = 0; u < 8; ++u) { h0v[u] = __float2half2_rn(0.f); h1v[u] = __float2half2_rn(0.f); }
    if (v0) {
      const __half2* p = H16S + (size_t)s * SLCN + (size_t)r0 * 8;
#pragma unroll
      for (int u = 0; u < 8; ++u) h0v[u] = p[u];
    }
    if (v1) {
      const __half2* p = H16S + (size_t)s * SLCN + (size_t)r1 * 8;
#pragma unroll
      for (int u = 0; u < 8; ++u) h1v[u] = p[u];
    }
#pragma unroll
    for (int u = 0; u < 8; ++u) {
      float2 a0 = __half22float2(h0v[u]);
      float2 a1 = __half22float2(h1v[u]);
      int k0 = s * 16 + u * 2;
#pragma unroll
      for (int half = 0; half < 2; ++half) {
        float f0 = half ? a0.y : a0.x;
        float f1 = half ? a1.y : a1.x;
        int k = k0 + half;
#pragma unroll
        for (int q = 0; q < 4; ++q) {
          float4 b = *(const float4*)&ws2[k * 16 + q * 4];
          acc0[q].x = fmaf(f0, b.x, acc0[q].x);
          acc0[q].y = fmaf(f0, b.y, acc0[q].y);
          acc0[q].z = fmaf(f0, b.z, acc0[q].z);
          acc0[q].w = fmaf(f0, b.w, acc0[q].w);
          acc1[q].x = fmaf(f1, b.x, acc1[q].x);
          acc1[q].y = fmaf(f1, b.y, acc1[q].y);
          acc1[q].z = fmaf(f1, b.z, acc1[q].z);
          acc1[q].w = fmaf(f1, b.w, acc1[q].w);
        }
      }
    }
  }
  if (v0) {
    __half2* op = O16 + (size_t)r0 * 8;
#pragma unroll
    for (int q = 0; q < 4; ++q) {
      op[q * 2]     = __floats2half2_rn(acc0[q].x, acc0[q].y);
      op[q * 2 + 1] = __floats2half2_rn(acc0[q].z, acc0[q].w);
    }
  }
  if (v1) {
    __half2* op = O16 + (size_t)r1 * 8;
#pragma unroll
    for (int q = 0; q < 4; ++q) {
      op[q * 2]     = __floats2half2_rn(acc1[q].x, acc1[q].y);
      op[q * 2 + 1] = __floats2half2_rn(acc1[q].z, acc1[q].w);
    }
  }
}

// ---------------- F=16 aggregation ----------------
// eagg16 gathers fp16 hw2 (3.2 MB table -> replicates into every XCD L2).

__global__ __launch_bounds__(256) void edge_agg16_kernel(
    const __half* __restrict__ feat, const int* __restrict__ nbr,
    const int* __restrict__ off, float* __restrict__ outf, int nseg) {
  int gid = blockIdx.x * 256 + threadIdx.x;
  int seg = gid >> 4;
  int c = gid & 15;
  if (seg >= nseg) return;
  int beg = off[seg], end = off[seg + 1];
  float a0 = 0.f, a1 = 0.f, a2 = 0.f, a3 = 0.f;
  int j = beg;
  for (; j + 8 <= end; j += 8) {
    int n0 = nbr[j],     n1 = nbr[j + 1], n2 = nbr[j + 2], n3 = nbr[j + 3];
    int n4 = nbr[j + 4], n5 = nbr[j + 5], n6 = nbr[j + 6], n7 = nbr[j + 7];
    float v0 = __half2float(feat[(size_t)n0 * 16 + c]);
    float v1 = __half2float(feat[(size_t)n1 * 16 + c]);
    float v2 = __half2float(feat[(size_t)n2 * 16 + c]);
    float v3 = __half2float(feat[(size_t)n3 * 16 + c]);
    float v4 = __half2float(feat[(size_t)n4 * 16 + c]);
    float v5 = __half2float(feat[(size_t)n5 * 16 + c]);
    float v6 = __half2float(feat[(size_t)n6 * 16 + c]);
    float v7 = __half2float(feat[(size_t)n7 * 16 + c]);
    a0 += v0 + v4; a1 += v1 + v5; a2 += v2 + v6; a3 += v3 + v7;
  }
  for (; j < end; ++j) a0 += __half2float(feat[(size_t)nbr[j] * 16 + c]);
  float inv = (end > beg) ? 1.f / (float)(end - beg) : 0.f;
  outf[(size_t)seg * 16 + c] = ((a0 + a1) + (a2 + a3)) * inv;
}

__global__ __launch_bounds__(256) void node_agg16_kernel(
    const float* __restrict__ feat, const int* __restrict__ nbr,
    const int* __restrict__ off, const float* __restrict__ bias,
    float* __restrict__ outf, int nseg) {
  int gid = blockIdx.x * 256 + threadIdx.x;
  int seg = gid >> 4;
  int c = gid & 15;
  if (seg >= nseg) return;
  int beg = off[seg], end = off[seg + 1];
  float a0 = 0.f, a1 = 0.f, a2 = 0.f, a3 = 0.f;
  int j = beg;
  for (; j + 8 <= end; j += 8) {
    int n0 = nbr[j],     n1 = nbr[j + 1], n2 = nbr[j + 2], n3 = nbr[j + 3];
    int n4 = nbr[j + 4], n5 = nbr[j + 5], n6 = nbr[j + 6], n7 = nbr[j + 7];
    float v0 = feat[(size_t)n0 * 16 + c];
    float v1 = feat[(size_t)n1 * 16 + c];
    float v2 = feat[(size_t)n2 * 16 + c];
    float v3 = feat[(size_t)n3 * 16 + c];
    float v4 = feat[(size_t)n4 * 16 + c];
    float v5 = feat[(size_t)n5 * 16 + c];
    float v6 = feat[(size_t)n6 * 16 + c];
    float v7 = feat[(size_t)n7 * 16 + c];
    a0 += v0 + v4; a1 += v1 + v5; a2 += v2 + v6; a3 += v3 + v7;
  }
  for (; j < end; ++j) a0 += feat[(size_t)nbr[j] * 16 + c];
  float inv = (end > beg) ? 1.f / (float)(end - beg) : 0.f;
  outf[(size_t)seg * 16 + c] = ((a0 + a1) + (a2 + a3)) * inv + bias[c];
}

// ---------------- launch ----------------

extern "C" void kernel_launch(void* const* d_in, const int* in_sizes, int n_in,
                              void* d_out, int out_size, void* d_ws, size_t ws_size,
                              hipStream_t stream) {
  const float* x        = (const float*)d_in[0];
  const int*   node_idx = (const int*)d_in[1];
  const int*   edge_idx = (const int*)d_in[2];
  const float* W1 = (const float*)d_in[4];
  const float* b1 = (const float*)d_in[5];
  const float* W2 = (const float*)d_in[6];
  const float* b2 = (const float*)d_in[7];
  float* out = (float*)d_out;

  const int n_nodes = in_sizes[0] / F1;  // 100000
  const int nnz     = in_sizes[1];       // 1600000
  const int n_edges = N_EDGES_C;         // 50000
  const int nC      = (nnz + CHUNK - 1) / CHUNK;   // 391
  const int Le      = EBINS * nC;
  const int Ln      = NBINS * nC;
  const int nbE     = (Le + 1023) / 1024;
  const int nbN     = (Ln + 1023) / 1024;

  char* ws = (char*)d_ws;
  // layout (bytes), high-water ~89.5 MB:
  int2*    epairs = (int2*)(ws + 0);            // 12.8M transient
  int2*    npairs = (int2*)(ws + 12800000);     // 12.8M transient
  __half2* h16s   = (__half2*)(ws + 0);         // 25.6M slice-major (after bin_scatter)
  __half2* xw16s  = (__half2*)(ws + 25600000);  // 25.6M slice-major
  __half2* ef16s  = (__half2*)(ws + 51200000);  // 12.8M slice-major
  __half*  hw216  = (__half*)(ws + 64000000);   //  3.2M fp16
  float*   ef2    = (float*)(ws + 70400000);    //  3.2M
  int*     enbr   = (int*)(ws + 73600000);      //  6.4M
  int*     nnbr   = (int*)(ws + 80000000);      //  6.4M
  int*     eoff   = (int*)(ws + 86400000);
  int*     noff   = (int*)(ws + 86600008);
  int*     echunkcnt = (int*)(ws + 87000016);
  int*     nchunkcnt = (int*)(ws + 87611540);
  int*     erunoff   = (int*)(ws + 88223064);
  int*     nrunoff   = (int*)(ws + 88834588);
  int*     ebinbase  = (int*)(ws + 89446112);
  int*     nbinbase  = (int*)(ws + 89447680);
  int*     epart     = (int*)(ws + 89449248);
  int*     npart     = (int*)(ws + 89450272);

  hist_chunk_kernel<<<nC, 256, 0, stream>>>(node_idx, edge_idx,
                                            echunkcnt, nchunkcnt, nnz);
  cscan_p1_kernel<<<nbE + nbN, 256, 0, stream>>>(echunkcnt, nchunkcnt,
                                                 epart, npart, Le, Ln, nbE);
  cscan_p2_kernel<<<1, 256, 0, stream>>>(epart, npart, ebinbase, nbinbase,
                                         nbE, nbN, nnz);
  cscan_p3_kernel<<<nbE + nbN, 256, 0, stream>>>(echunkcnt, nchunkcnt,
                                                 epart, npart, erunoff, nrunoff,
                                                 ebinbase, nbinbase, Le, Ln, nbE, nC);
  stage_kernel<<<nC, 256, 0, stream>>>(node_idx, edge_idx, erunoff, nrunoff,
                                       epairs, npairs, nnz);
  bin_scatter_kernel<<<EBINS + NBINS, 256, 0, stream>>>(epairs, npairs,
                                                        ebinbase, nbinbase,
                                                        eoff, noff, enbr, nnbr,
                                                        n_edges, n_nodes);

  // layer 1 (fp16 slice-major message path)
  gemm1_kernel<<<(n_nodes + 127) / 128, 256, 0, stream>>>(x, W1, xw16s, n_nodes);
  edge_agg128_kernel<<<8 * ((n_edges + 3) / 4), 256, 0, stream>>>(
      xw16s, enbr, eoff, ef16s, n_edges);
  node_agg128_kernel<<<8 * ((n_nodes + 3) / 4), 256, 0, stream>>>(
      ef16s, nnbr, noff, b1, h16s, n_nodes);

  // layer 2
  gemm2_kernel<<<(n_nodes + 511) / 512, 256, 0, stream>>>(h16s, W2,
                                                          (__half2*)hw216, n_nodes);
  edge_agg16_kernel<<<(n_edges * 16 + 255) / 256, 256, 0, stream>>>(
      hw216, enbr, eoff, ef2, n_edges);
  node_agg16_kernel<<<(n_nodes * 16 + 255) / 256, 256, 0, stream>>>(
      ef2, nnbr, noff, b2, out, n_nodes);
}

// Round 10
// 404.957 us; speedup vs baseline: 1.4564x; 1.4564x over previous
//
#include <hip/hip_runtime.h>
#include <hip/hip_fp16.h>

// N_NODES=100000, N_EDGES=50000, NNZ=1600000, dims 128->128->16, fp32 I/O.
// Message path fp16 (flat [row][128] layout), accumulate fp32.
// CSR build: LDS-only counting sort (R6/R7 structure, measured cheap).
// F=128 aggs: wave=segment, lane=(row-slot 0-3, 16B chunk 0-15); dwordx4
// gathers, x4 unroll -> 16 rows (4KB) in flight/wave, 1/4 the VMEM insts of R8.
// R9's XCD slicing is REVERTED: it made FETCH 150->33MB but 8x wave count
// and per-wave overhead cost 3x duration (203us) -- overhead > latency saved.

#define N_EDGES_C 50000
#define F1 128
#define F2 16
#define CHUNK 4096
#define EBIN_SHIFT 7
#define NBIN_SHIFT 8
#define EBINS 391
#define NBINS 391

// ---------------- CSR build ----------------

__global__ __launch_bounds__(256) void hist_chunk_kernel(
    const int* __restrict__ node_idx, const int* __restrict__ edge_idx,
    int* __restrict__ echunkcnt, int* __restrict__ nchunkcnt, int nnz) {
  __shared__ int ebc[EBINS], nbc[NBINS];
  const int t = threadIdx.x;
  for (int b = t; b < EBINS; b += 256) ebc[b] = 0;
  for (int b = t; b < NBINS; b += 256) nbc[b] = 0;
  __syncthreads();
  const int base = blockIdx.x * CHUNK;
  int end = base + CHUNK; if (end > nnz) end = nnz;
  for (int i = base + t; i < end; i += 256) {
    atomicAdd(&ebc[edge_idx[i] >> EBIN_SHIFT], 1);
    atomicAdd(&nbc[node_idx[i] >> NBIN_SHIFT], 1);
  }
  __syncthreads();
  const int nC = gridDim.x;
  for (int b = t; b < EBINS; b += 256) echunkcnt[b * nC + blockIdx.x] = ebc[b];
  for (int b = t; b < NBINS; b += 256) nchunkcnt[b * nC + blockIdx.x] = nbc[b];
}

__global__ __launch_bounds__(256) void cscan_p1_kernel(
    const int* __restrict__ ecc, const int* __restrict__ ncc,
    int* __restrict__ epart, int* __restrict__ npart,
    int Le, int Ln, int nbE) {
  __shared__ int red[256];
  const int t = threadIdx.x;
  const int b = blockIdx.x;
  const int* src; int L; int* dst; int bb;
  if (b < nbE) { src = ecc; L = Le; dst = epart; bb = b; }
  else         { src = ncc; L = Ln; dst = npart; bb = b - nbE; }
  int base = bb * 1024 + t * 4;
  int s = 0;
#pragma unroll
  for (int j = 0; j < 4; ++j) { int i = base + j; if (i < L) s += src[i]; }
  red[t] = s;
  __syncthreads();
  for (int d = 128; d > 0; d >>= 1) {
    if (t < d) red[t] += red[t + d];
    __syncthreads();
  }
  if (t == 0) dst[bb] = red[0];
}

__global__ __launch_bounds__(256) void cscan_p2_kernel(
    int* __restrict__ epart, int* __restrict__ npart,
    int* __restrict__ ebinbase, int* __restrict__ nbinbase,
    int nbE, int nbN, int nnz) {
  __shared__ int se[256], sn[256];
  const int t = threadIdx.x;
  se[t] = (t < nbE) ? epart[t] : 0;
  sn[t] = (t < nbN) ? npart[t] : 0;
  __syncthreads();
  for (int d = 1; d < 256; d <<= 1) {
    int ve = (t >= d) ? se[t - d] : 0;
    int vn = (t >= d) ? sn[t - d] : 0;
    __syncthreads();
    se[t] += ve; sn[t] += vn;
    __syncthreads();
  }
  if (t < nbE) epart[t] = (t > 0) ? se[t - 1] : 0;
  if (t < nbN) npart[t] = (t > 0) ? sn[t - 1] : 0;
  if (t == 0) { ebinbase[EBINS] = nnz; nbinbase[NBINS] = nnz; }
}

__global__ __launch_bounds__(256) void cscan_p3_kernel(
    const int* __restrict__ ecc, const int* __restrict__ ncc,
    const int* __restrict__ epart, const int* __restrict__ npart,
    int* __restrict__ erunoff, int* __restrict__ nrunoff,
    int* __restrict__ ebinbase, int* __restrict__ nbinbase,
    int Le, int Ln, int nbE, int nC) {
  __shared__ int red[256];
  const int t = threadIdx.x;
  const int b = blockIdx.x;
  const int* src; const int* part; int L; int* ro; int* bba; int bb;
  if (b < nbE) { src = ecc; part = epart; L = Le; ro = erunoff; bba = ebinbase; bb = b; }
  else         { src = ncc; part = npart; L = Ln; ro = nrunoff; bba = nbinbase; bb = b - nbE; }
  int base = bb * 1024 + t * 4;
  int v[4]; int s = 0;
#pragma unroll
  for (int j = 0; j < 4; ++j) { int i = base + j; v[j] = (i < L) ? src[i] : 0; s += v[j]; }
  red[t] = s;
  __syncthreads();
  for (int d = 1; d < 256; d <<= 1) {
    int x = (t >= d) ? red[t - d] : 0;
    __syncthreads();
    red[t] += x;
    __syncthreads();
  }
  int run = part[bb] + ((t > 0) ? red[t - 1] : 0);
#pragma unroll
  for (int j = 0; j < 4; ++j) {
    int i = base + j;
    if (i < L) {
      ro[i] = run;
      if (i % nC == 0) bba[i / nC] = run;
      run += v[j];
    }
  }
}

__global__ __launch_bounds__(256) void stage_kernel(
    const int* __restrict__ node_idx, const int* __restrict__ edge_idx,
    const int* __restrict__ erunoff, const int* __restrict__ nrunoff,
    int2* __restrict__ epairs, int2* __restrict__ npairs, int nnz) {
  __shared__ int ecur[EBINS], ncur[NBINS];
  const int t = threadIdx.x;
  const int nC = gridDim.x;
  for (int b = t; b < EBINS; b += 256) ecur[b] = erunoff[b * nC + blockIdx.x];
  for (int b = t; b < NBINS; b += 256) ncur[b] = nrunoff[b * nC + blockIdx.x];
  __syncthreads();
  const int base = blockIdx.x * CHUNK;
  int end = base + CHUNK; if (end > nnz) end = nnz;
  for (int i = base + t; i < end; i += 256) {
    int e = edge_idx[i];
    int n = node_idx[i];
    int p = atomicAdd(&ecur[e >> EBIN_SHIFT], 1);
    epairs[p] = make_int2(e, n);
    int q = atomicAdd(&ncur[n >> NBIN_SHIFT], 1);
    npairs[q] = make_int2(n, e);
  }
}

__global__ __launch_bounds__(256) void bin_scatter_kernel(
    const int2* __restrict__ epairs, const int2* __restrict__ npairs,
    const int* __restrict__ ebinbase, const int* __restrict__ nbinbase,
    int* __restrict__ eoff, int* __restrict__ noff,
    int* __restrict__ enbr, int* __restrict__ nnbr,
    int n_edges, int n_nodes) {
  __shared__ int cnt[256];
  __shared__ int scn[256];
  const int bid = blockIdx.x;
  const int t = threadIdx.x;
  if (bid < EBINS) {
    const int e0 = bid << EBIN_SHIFT;
    const int ne = min(1 << EBIN_SHIFT, n_edges - e0);
    const int beg = ebinbase[bid], end = ebinbase[bid + 1];
    if (t < 128) cnt[t] = 0;
    __syncthreads();
    for (int j = beg + t; j < end; j += 256) atomicAdd(&cnt[epairs[j].x & 127], 1);
    __syncthreads();
    if (t < 128) scn[t] = cnt[t];
    __syncthreads();
    for (int d = 1; d < 128; d <<= 1) {
      int x = 0;
      if (t < 128 && t >= d) x = scn[t - d];
      __syncthreads();
      if (t < 128) scn[t] += x;
      __syncthreads();
    }
    int pos0 = 0;
    if (t < 128) {
      int excl = (t > 0) ? scn[t - 1] : 0;
      pos0 = beg + excl;
      if (t < ne) eoff[e0 + t] = pos0;
    }
    __syncthreads();
    if (t < 128) scn[t] = pos0;
    __syncthreads();
    for (int j = beg + t; j < end; j += 256) {
      int2 p = epairs[j];
      int pos = atomicAdd(&scn[p.x & 127], 1);
      enbr[pos] = p.y;
    }
    if (bid == EBINS - 1 && t == 0) eoff[n_edges] = end;
  } else {
    const int b = bid - EBINS;
    const int n0 = b << NBIN_SHIFT;
    const int nn = min(1 << NBIN_SHIFT, n_nodes - n0);
    const int beg = nbinbase[b], end = nbinbase[b + 1];
    cnt[t] = 0;
    __syncthreads();
    for (int j = beg + t; j < end; j += 256) atomicAdd(&cnt[npairs[j].x & 255], 1);
    __syncthreads();
    scn[t] = cnt[t];
    __syncthreads();
    for (int d = 1; d < 256; d <<= 1) {
      int x = (t >= d) ? scn[t - d] : 0;
      __syncthreads();
      scn[t] += x;
      __syncthreads();
    }
    int excl = (t > 0) ? scn[t - 1] : 0;
    int pos0 = beg + excl;
    if (t < nn) noff[n0 + t] = pos0;
    __syncthreads();
    scn[t] = pos0;
    __syncthreads();
    for (int j = beg + t; j < end; j += 256) {
      int2 p = npairs[j];
      int pos = atomicAdd(&scn[p.x & 255], 1);
      nnbr[pos] = p.y;
    }
    if (bid == EBINS + NBINS - 1 && t == 0) noff[n_nodes] = end;
  }
}

// ---------------- GEMM1: xw16[M x 128] = x[M x 128] @ W1, flat fp16 out ----------------

__global__ __launch_bounds__(256) void gemm1_kernel(
    const float* __restrict__ A, const float* __restrict__ B,
    __half* __restrict__ C16, int M) {
  __shared__ float xs[128][36];
  __shared__ float wsh[32][128];

  const int t = threadIdx.x;
  const int tx = t & 15;
  const int ty = t >> 4;
  const int bm = blockIdx.x * 128;

  float acc[8][8];
#pragma unroll
  for (int i = 0; i < 8; ++i)
#pragma unroll
    for (int j = 0; j < 8; ++j) acc[i][j] = 0.f;

  for (int kt = 0; kt < 4; ++kt) {
#pragma unroll
    for (int i = 0; i < 4; ++i) {
      int lin = i * 256 + t;
      int row = lin >> 3;
      int c4 = lin & 7;
      int grow = bm + row;
      float4 v = make_float4(0.f, 0.f, 0.f, 0.f);
      if (grow < M) v = *(const float4*)(A + (size_t)grow * 128 + kt * 32 + c4 * 4);
      *(float4*)&xs[row][c4 * 4] = v;
    }
#pragma unroll
    for (int i = 0; i < 4; ++i) {
      int lin = i * 256 + t;
      int k = lin >> 5;
      int c4 = lin & 31;
      *(float4*)&wsh[k][c4 * 4] = *(const float4*)(B + (size_t)(kt * 32 + k) * 128 + c4 * 4);
    }
    __syncthreads();

#pragma unroll 4
    for (int k = 0; k < 32; ++k) {
      float a[8], b[8];
#pragma unroll
      for (int j = 0; j < 4; ++j) {
        a[j]     = xs[ty * 4 + j][k];
        a[4 + j] = xs[ty * 4 + 64 + j][k];
      }
      float4 b0 = *(const float4*)&wsh[k][tx * 4];
      float4 b1 = *(const float4*)&wsh[k][tx * 4 + 64];
      b[0] = b0.x; b[1] = b0.y; b[2] = b0.z; b[3] = b0.w;
      b[4] = b1.x; b[5] = b1.y; b[6] = b1.z; b[7] = b1.w;
#pragma unroll
      for (int i = 0; i < 8; ++i)
#pragma unroll
        for (int j = 0; j < 8; ++j) acc[i][j] = fmaf(a[i], b[j], acc[i][j]);
    }
    __syncthreads();
  }

#pragma unroll
  for (int i = 0; i < 8; ++i) {
    int row = (i < 4) ? (ty * 4 + i) : (ty * 4 + 64 + (i - 4));
    int grow = bm + row;
    if (grow < M) {
      __half2* rp = (__half2*)(C16 + (size_t)grow * 128);
      rp[tx * 2]          = __floats2half2_rn(acc[i][0], acc[i][1]);
      rp[tx * 2 + 1]      = __floats2half2_rn(acc[i][2], acc[i][3]);
      rp[32 + tx * 2]     = __floats2half2_rn(acc[i][4], acc[i][5]);
      rp[32 + tx * 2 + 1] = __floats2half2_rn(acc[i][6], acc[i][7]);
    }
  }
}

// ---------------- F=128 aggregation: 4-row x 16-chunk dwordx4 gathers ----------------

__device__ __forceinline__ void acc_h8(float* ax, float4 v) {
  const __half2* h = (const __half2*)&v;
#pragma unroll
  for (int q = 0; q < 4; ++q) {
    float2 f = __half22float2(h[q]);
    ax[2 * q] += f.x; ax[2 * q + 1] += f.y;
  }
}

__global__ __launch_bounds__(256) void edge_agg128_kernel(
    const float4* __restrict__ feat,   // [rows][16] f4 view of half[128] rows
    const int* __restrict__ nbr, const int* __restrict__ off,
    float4* __restrict__ outf, int nseg) {
  int w = (blockIdx.x * 256 + threadIdx.x) >> 6;
  if (w >= nseg) return;
  const int lane = threadIdx.x & 63;
  const int r = lane >> 4;   // row slot 0..3
  const int f = lane & 15;   // 16B chunk in row
  int beg = off[w], end = off[w + 1];
  float ax[8];
#pragma unroll
  for (int i = 0; i < 8; ++i) ax[i] = 0.f;
  int k = beg + r;
  for (; k + 12 < end; k += 16) {
    int n0 = nbr[k], n1 = nbr[k + 4], n2 = nbr[k + 8], n3 = nbr[k + 12];
    float4 v0 = feat[(size_t)n0 * 16 + f];
    float4 v1 = feat[(size_t)n1 * 16 + f];
    float4 v2 = feat[(size_t)n2 * 16 + f];
    float4 v3 = feat[(size_t)n3 * 16 + f];
    acc_h8(ax, v0); acc_h8(ax, v1); acc_h8(ax, v2); acc_h8(ax, v3);
  }
  for (; k < end; k += 4) acc_h8(ax, feat[(size_t)nbr[k] * 16 + f]);
#pragma unroll
  for (int i = 0; i < 8; ++i) {
    ax[i] += __shfl_xor(ax[i], 16, 64);
    ax[i] += __shfl_xor(ax[i], 32, 64);
  }
  if (r == 0) {
    float inv = (end > beg) ? 1.f / (float)(end - beg) : 0.f;
    union { float4 f4; __half2 h[4]; } u;
#pragma unroll
    for (int q = 0; q < 4; ++q)
      u.h[q] = __floats2half2_rn(ax[2 * q] * inv, ax[2 * q + 1] * inv);
    outf[(size_t)w * 16 + f] = u.f4;
  }
}

__global__ __launch_bounds__(256) void node_agg128_kernel(
    const float4* __restrict__ feat,   // ef16 rows
    const int* __restrict__ nbr, const int* __restrict__ off,
    const float* __restrict__ bias,
    float4* __restrict__ outf, int nseg) {  // h16 rows
  int w = (blockIdx.x * 256 + threadIdx.x) >> 6;
  if (w >= nseg) return;
  const int lane = threadIdx.x & 63;
  const int r = lane >> 4;
  const int f = lane & 15;
  int beg = off[w], end = off[w + 1];
  float ax[8];
#pragma unroll
  for (int i = 0; i < 8; ++i) ax[i] = 0.f;
  int k = beg + r;
  for (; k + 12 < end; k += 16) {
    int e0 = nbr[k], e1 = nbr[k + 4], e2 = nbr[k + 8], e3 = nbr[k + 12];
    float4 v0 = feat[(size_t)e0 * 16 + f];
    float4 v1 = feat[(size_t)e1 * 16 + f];
    float4 v2 = feat[(size_t)e2 * 16 + f];
    float4 v3 = feat[(size_t)e3 * 16 + f];
    acc_h8(ax, v0); acc_h8(ax, v1); acc_h8(ax, v2); acc_h8(ax, v3);
  }
  for (; k < end; k += 4) acc_h8(ax, feat[(size_t)nbr[k] * 16 + f]);
#pragma unroll
  for (int i = 0; i < 8; ++i) {
    ax[i] += __shfl_xor(ax[i], 16, 64);
    ax[i] += __shfl_xor(ax[i], 32, 64);
  }
  if (r == 0) {
    float inv = (end > beg) ? 1.f / (float)(end - beg) : 0.f;
    float4 blo = ((const float4*)bias)[2 * f];
    float4 bhi = ((const float4*)bias)[2 * f + 1];
    float bb[8] = {blo.x, blo.y, blo.z, blo.w, bhi.x, bhi.y, bhi.z, bhi.w};
    union { float4 f4; __half2 h[4]; } u;
#pragma unroll
    for (int q = 0; q < 4; ++q) {
      float hx = fmaxf(ax[2 * q] * inv + bb[2 * q], 0.f);       // + b1, ReLU
      float hy = fmaxf(ax[2 * q + 1] * inv + bb[2 * q + 1], 0.f);
      u.h[q] = __floats2half2_rn(hx, hy);
    }
    outf[(size_t)w * 16 + f] = u.f4;
  }
}

// ---------------- GEMM2: hw2_16[M x 16] (fp16) = h16[M x 128] @ W2[128 x 16] ----------

__global__ __launch_bounds__(256) void gemm2_kernel(
    const __half* __restrict__ H16, const float* __restrict__ W2,
    __half2* __restrict__ O16, int M) {
  __shared__ float ws2[128 * 16];
  const int t = threadIdx.x;
#pragma unroll
  for (int i = 0; i < 8; ++i) ws2[i * 256 + t] = W2[i * 256 + t];
  __syncthreads();

  int r0 = blockIdx.x * 512 + t;
  int r1 = r0 + 256;
  bool v0 = r0 < M, v1 = r1 < M;
  const __half2* h0 = (const __half2*)(H16 + (size_t)r0 * 128);
  const __half2* h1 = (const __half2*)(H16 + (size_t)r1 * 128);

  float4 acc0[4], acc1[4];
#pragma unroll
  for (int q = 0; q < 4; ++q) {
    acc0[q] = make_float4(0.f, 0.f, 0.f, 0.f);
    acc1[q] = make_float4(0.f, 0.f, 0.f, 0.f);
  }

  for (int k4 = 0; k4 < 32; ++k4) {
    float2 f00 = make_float2(0.f, 0.f), f01 = make_float2(0.f, 0.f);
    float2 f10 = make_float2(0.f, 0.f), f11 = make_float2(0.f, 0.f);
    if (v0) { f00 = __half22float2(h0[2 * k4]); f01 = __half22float2(h0[2 * k4 + 1]); }
    if (v1) { f10 = __half22float2(h1[2 * k4]); f11 = __half22float2(h1[2 * k4 + 1]); }
    const float a0s[4] = {f00.x, f00.y, f01.x, f01.y};
    const float a1s[4] = {f10.x, f10.y, f11.x, f11.y};
#pragma unroll
    for (int j = 0; j < 4; ++j) {
      int k = k4 * 4 + j;
#pragma unroll
      for (int q = 0; q < 4; ++q) {
        float4 b = *(const float4*)&ws2[k * 16 + q * 4];
        acc0[q].x = fmaf(a0s[j], b.x, acc0[q].x);
        acc0[q].y = fmaf(a0s[j], b.y, acc0[q].y);
        acc0[q].z = fmaf(a0s[j], b.z, acc0[q].z);
        acc0[q].w = fmaf(a0s[j], b.w, acc0[q].w);
        acc1[q].x = fmaf(a1s[j], b.x, acc1[q].x);
        acc1[q].y = fmaf(a1s[j], b.y, acc1[q].y);
        acc1[q].z = fmaf(a1s[j], b.z, acc1[q].z);
        acc1[q].w = fmaf(a1s[j], b.w, acc1[q].w);
      }
    }
  }
  if (v0) {
    __half2* op = O16 + (size_t)r0 * 8;
#pragma unroll
    for (int q = 0; q < 4; ++q) {
      op[q * 2]     = __floats2half2_rn(acc0[q].x, acc0[q].y);
      op[q * 2 + 1] = __floats2half2_rn(acc0[q].z, acc0[q].w);
    }
  }
  if (v1) {
    __half2* op = O16 + (size_t)r1 * 8;
#pragma unroll
    for (int q = 0; q < 4; ++q) {
      op[q * 2]     = __floats2half2_rn(acc1[q].x, acc1[q].y);
      op[q * 2 + 1] = __floats2half2_rn(acc1[q].z, acc1[q].w);
    }
  }
}

// ---------------- F=16 aggregation ----------------

__global__ __launch_bounds__(256) void edge_agg16_kernel(
    const __half* __restrict__ feat, const int* __restrict__ nbr,
    const int* __restrict__ off, float* __restrict__ outf, int nseg) {
  int gid = blockIdx.x * 256 + threadIdx.x;
  int seg = gid >> 4;
  int c = gid & 15;
  if (seg >= nseg) return;
  int beg = off[seg], end = off[seg + 1];
  float a0 = 0.f, a1 = 0.f, a2 = 0.f, a3 = 0.f;
  int j = beg;
  for (; j + 8 <= end; j += 8) {
    int n0 = nbr[j],     n1 = nbr[j + 1], n2 = nbr[j + 2], n3 = nbr[j + 3];
    int n4 = nbr[j + 4], n5 = nbr[j + 5], n6 = nbr[j + 6], n7 = nbr[j + 7];
    float v0 = __half2float(feat[(size_t)n0 * 16 + c]);
    float v1 = __half2float(feat[(size_t)n1 * 16 + c]);
    float v2 = __half2float(feat[(size_t)n2 * 16 + c]);
    float v3 = __half2float(feat[(size_t)n3 * 16 + c]);
    float v4 = __half2float(feat[(size_t)n4 * 16 + c]);
    float v5 = __half2float(feat[(size_t)n5 * 16 + c]);
    float v6 = __half2float(feat[(size_t)n6 * 16 + c]);
    float v7 = __half2float(feat[(size_t)n7 * 16 + c]);
    a0 += v0 + v4; a1 += v1 + v5; a2 += v2 + v6; a3 += v3 + v7;
  }
  for (; j < end; ++j) a0 += __half2float(feat[(size_t)nbr[j] * 16 + c]);
  float inv = (end > beg) ? 1.f / (float)(end - beg) : 0.f;
  outf[(size_t)seg * 16 + c] = ((a0 + a1) + (a2 + a3)) * inv;
}

__global__ __launch_bounds__(256) void node_agg16_kernel(
    const float* __restrict__ feat, const int* __restrict__ nbr,
    const int* __restrict__ off, const float* __restrict__ bias,
    float* __restrict__ outf, int nseg) {
  int gid = blockIdx.x * 256 + threadIdx.x;
  int seg = gid >> 4;
  int c = gid & 15;
  if (seg >= nseg) return;
  int beg = off[seg], end = off[seg + 1];
  float a0 = 0.f, a1 = 0.f, a2 = 0.f, a3 = 0.f;
  int j = beg;
  for (; j + 8 <= end; j += 8) {
    int n0 = nbr[j],     n1 = nbr[j + 1], n2 = nbr[j + 2], n3 = nbr[j + 3];
    int n4 = nbr[j + 4], n5 = nbr[j + 5], n6 = nbr[j + 6], n7 = nbr[j + 7];
    float v0 = feat[(size_t)n0 * 16 + c];
    float v1 = feat[(size_t)n1 * 16 + c];
    float v2 = feat[(size_t)n2 * 16 + c];
    float v3 = feat[(size_t)n3 * 16 + c];
    float v4 = feat[(size_t)n4 * 16 + c];
    float v5 = feat[(size_t)n5 * 16 + c];
    float v6 = feat[(size_t)n6 * 16 + c];
    float v7 = feat[(size_t)n7 * 16 + c];
    a0 += v0 + v4; a1 += v1 + v5; a2 += v2 + v6; a3 += v3 + v7;
  }
  for (; j < end; ++j) a0 += feat[(size_t)nbr[j] * 16 + c];
  float inv = (end > beg) ? 1.f / (float)(end - beg) : 0.f;
  outf[(size_t)seg * 16 + c] = ((a0 + a1) + (a2 + a3)) * inv + bias[c];
}

// ---------------- launch ----------------

extern "C" void kernel_launch(void* const* d_in, const int* in_sizes, int n_in,
                              void* d_out, int out_size, void* d_ws, size_t ws_size,
                              hipStream_t stream) {
  const float* x        = (const float*)d_in[0];
  const int*   node_idx = (const int*)d_in[1];
  const int*   edge_idx = (const int*)d_in[2];
  const float* W1 = (const float*)d_in[4];
  const float* b1 = (const float*)d_in[5];
  const float* W2 = (const float*)d_in[6];
  const float* b2 = (const float*)d_in[7];
  float* out = (float*)d_out;

  const int n_nodes = in_sizes[0] / F1;  // 100000
  const int nnz     = in_sizes[1];       // 1600000
  const int n_edges = N_EDGES_C;         // 50000
  const int nC      = (nnz + CHUNK - 1) / CHUNK;   // 391
  const int Le      = EBINS * nC;
  const int Ln      = NBINS * nC;
  const int nbE     = (Le + 1023) / 1024;
  const int nbN     = (Ln + 1023) / 1024;

  char* ws = (char*)d_ws;
  int2*    epairs = (int2*)(ws + 0);            // 12.8M transient
  int2*    npairs = (int2*)(ws + 12800000);     // 12.8M transient
  __half*  h16    = (__half*)(ws + 0);          // 25.6M flat (after bin_scatter)
  __half*  xw16   = (__half*)(ws + 25600000);   // 25.6M flat
  __half*  ef16   = (__half*)(ws + 51200000);   // 12.8M flat
  __half*  hw216  = (__half*)(ws + 64000000);   //  3.2M fp16
  float*   ef2    = (float*)(ws + 70400000);    //  3.2M
  int*     enbr   = (int*)(ws + 73600000);      //  6.4M
  int*     nnbr   = (int*)(ws + 80000000);      //  6.4M
  int*     eoff   = (int*)(ws + 86400000);
  int*     noff   = (int*)(ws + 86600008);
  int*     echunkcnt = (int*)(ws + 87000016);
  int*     nchunkcnt = (int*)(ws + 87611540);
  int*     erunoff   = (int*)(ws + 88223064);
  int*     nrunoff   = (int*)(ws + 88834588);
  int*     ebinbase  = (int*)(ws + 89446112);
  int*     nbinbase  = (int*)(ws + 89447680);
  int*     epart     = (int*)(ws + 89449248);
  int*     npart     = (int*)(ws + 89450272);

  hist_chunk_kernel<<<nC, 256, 0, stream>>>(node_idx, edge_idx,
                                            echunkcnt, nchunkcnt, nnz);
  cscan_p1_kernel<<<nbE + nbN, 256, 0, stream>>>(echunkcnt, nchunkcnt,
                                                 epart, npart, Le, Ln, nbE);
  cscan_p2_kernel<<<1, 256, 0, stream>>>(epart, npart, ebinbase, nbinbase,
                                         nbE, nbN, nnz);
  cscan_p3_kernel<<<nbE + nbN, 256, 0, stream>>>(echunkcnt, nchunkcnt,
                                                 epart, npart, erunoff, nrunoff,
                                                 ebinbase, nbinbase, Le, Ln, nbE, nC);
  stage_kernel<<<nC, 256, 0, stream>>>(node_idx, edge_idx, erunoff, nrunoff,
                                       epairs, npairs, nnz);
  bin_scatter_kernel<<<EBINS + NBINS, 256, 0, stream>>>(epairs, npairs,
                                                        ebinbase, nbinbase,
                                                        eoff, noff, enbr, nnbr,
                                                        n_edges, n_nodes);

  // layer 1 (fp16 flat message path)
  gemm1_kernel<<<(n_nodes + 127) / 128, 256, 0, stream>>>(x, W1, xw16, n_nodes);
  edge_agg128_kernel<<<(n_edges * 64 + 255) / 256, 256, 0, stream>>>(
      (const float4*)xw16, enbr, eoff, (float4*)ef16, n_edges);
  node_agg128_kernel<<<(n_nodes * 64 + 255) / 256, 256, 0, stream>>>(
      (const float4*)ef16, nnbr, noff, b1, (float4*)h16, n_nodes);

  // layer 2
  gemm2_kernel<<<(n_nodes + 511) / 512, 256, 0, stream>>>(h16, W2,
                                                          (__half2*)hw216, n_nodes);
  edge_agg16_kernel<<<(n_edges * 16 + 255) / 256, 256, 0, stream>>>(
      hw216, enbr, eoff, ef2, n_edges);
  node_agg16_kernel<<<(n_nodes * 16 + 255) / 256, 256, 0, stream>>>(
      ef2, nnbr, noff, b2, out, n_nodes);
}

// Round 11
// 370.370 us; speedup vs baseline: 1.5924x; 1.0934x over previous
//
#include <hip/hip_runtime.h>
#include <hip/hip_fp16.h>

// N_NODES=100000, N_EDGES=50000, NNZ=1600000, dims 128->128->16, fp32 I/O.
// Message path fp16 (flat [row][128]), accumulate fp32. CSR: LDS-only counting sort.
// F=128 aggs: 4-row x 16B-chunk dwordx4 gathers (R10, verified).
// gemm1: MFMA f32_16x16x32_f16 (fp16 in, fp32 acc) -- fp32 VALU path was 32% of
// 157TF at 66us; matrix path is ~memory-floor ~14us. W1 pre-transposed fp16 once.

#define N_EDGES_C 50000
#define F1 128
#define F2 16
#define CHUNK 4096
#define EBIN_SHIFT 7
#define NBIN_SHIFT 8
#define EBINS 391
#define NBINS 391

typedef __attribute__((ext_vector_type(8))) _Float16 half8;
typedef __attribute__((ext_vector_type(4))) float f32x4;

// ---------------- CSR build ----------------

__global__ __launch_bounds__(256) void hist_chunk_kernel(
    const int* __restrict__ node_idx, const int* __restrict__ edge_idx,
    int* __restrict__ echunkcnt, int* __restrict__ nchunkcnt, int nnz) {
  __shared__ int ebc[EBINS], nbc[NBINS];
  const int t = threadIdx.x;
  for (int b = t; b < EBINS; b += 256) ebc[b] = 0;
  for (int b = t; b < NBINS; b += 256) nbc[b] = 0;
  __syncthreads();
  const int base = blockIdx.x * CHUNK;
  int end = base + CHUNK; if (end > nnz) end = nnz;
  for (int i = base + t; i < end; i += 256) {
    atomicAdd(&ebc[edge_idx[i] >> EBIN_SHIFT], 1);
    atomicAdd(&nbc[node_idx[i] >> NBIN_SHIFT], 1);
  }
  __syncthreads();
  const int nC = gridDim.x;
  for (int b = t; b < EBINS; b += 256) echunkcnt[b * nC + blockIdx.x] = ebc[b];
  for (int b = t; b < NBINS; b += 256) nchunkcnt[b * nC + blockIdx.x] = nbc[b];
}

__global__ __launch_bounds__(256) void cscan_p1_kernel(
    const int* __restrict__ ecc, const int* __restrict__ ncc,
    int* __restrict__ epart, int* __restrict__ npart,
    int Le, int Ln, int nbE) {
  __shared__ int red[256];
  const int t = threadIdx.x;
  const int b = blockIdx.x;
  const int* src; int L; int* dst; int bb;
  if (b < nbE) { src = ecc; L = Le; dst = epart; bb = b; }
  else         { src = ncc; L = Ln; dst = npart; bb = b - nbE; }
  int base = bb * 1024 + t * 4;
  int s = 0;
#pragma unroll
  for (int j = 0; j < 4; ++j) { int i = base + j; if (i < L) s += src[i]; }
  red[t] = s;
  __syncthreads();
  for (int d = 128; d > 0; d >>= 1) {
    if (t < d) red[t] += red[t + d];
    __syncthreads();
  }
  if (t == 0) dst[bb] = red[0];
}

__global__ __launch_bounds__(256) void cscan_p2_kernel(
    int* __restrict__ epart, int* __restrict__ npart,
    int* __restrict__ ebinbase, int* __restrict__ nbinbase,
    int nbE, int nbN, int nnz) {
  __shared__ int se[256], sn[256];
  const int t = threadIdx.x;
  se[t] = (t < nbE) ? epart[t] : 0;
  sn[t] = (t < nbN) ? npart[t] : 0;
  __syncthreads();
  for (int d = 1; d < 256; d <<= 1) {
    int ve = (t >= d) ? se[t - d] : 0;
    int vn = (t >= d) ? sn[t - d] : 0;
    __syncthreads();
    se[t] += ve; sn[t] += vn;
    __syncthreads();
  }
  if (t < nbE) epart[t] = (t > 0) ? se[t - 1] : 0;
  if (t < nbN) npart[t] = (t > 0) ? sn[t - 1] : 0;
  if (t == 0) { ebinbase[EBINS] = nnz; nbinbase[NBINS] = nnz; }
}

__global__ __launch_bounds__(256) void cscan_p3_kernel(
    const int* __restrict__ ecc, const int* __restrict__ ncc,
    const int* __restrict__ epart, const int* __restrict__ npart,
    int* __restrict__ erunoff, int* __restrict__ nrunoff,
    int* __restrict__ ebinbase, int* __restrict__ nbinbase,
    int Le, int Ln, int nbE, int nC) {
  __shared__ int red[256];
  const int t = threadIdx.x;
  const int b = blockIdx.x;
  const int* src; const int* part; int L; int* ro; int* bba; int bb;
  if (b < nbE) { src = ecc; part = epart; L = Le; ro = erunoff; bba = ebinbase; bb = b; }
  else         { src = ncc; part = npart; L = Ln; ro = nrunoff; bba = nbinbase; bb = b - nbE; }
  int base = bb * 1024 + t * 4;
  int v[4]; int s = 0;
#pragma unroll
  for (int j = 0; j < 4; ++j) { int i = base + j; v[j] = (i < L) ? src[i] : 0; s += v[j]; }
  red[t] = s;
  __syncthreads();
  for (int d = 1; d < 256; d <<= 1) {
    int x = (t >= d) ? red[t - d] : 0;
    __syncthreads();
    red[t] += x;
    __syncthreads();
  }
  int run = part[bb] + ((t > 0) ? red[t - 1] : 0);
#pragma unroll
  for (int j = 0; j < 4; ++j) {
    int i = base + j;
    if (i < L) {
      ro[i] = run;
      if (i % nC == 0) bba[i / nC] = run;
      run += v[j];
    }
  }
}

__global__ __launch_bounds__(256) void stage_kernel(
    const int* __restrict__ node_idx, const int* __restrict__ edge_idx,
    const int* __restrict__ erunoff, const int* __restrict__ nrunoff,
    int2* __restrict__ epairs, int2* __restrict__ npairs, int nnz) {
  __shared__ int ecur[EBINS], ncur[NBINS];
  const int t = threadIdx.x;
  const int nC = gridDim.x;
  for (int b = t; b < EBINS; b += 256) ecur[b] = erunoff[b * nC + blockIdx.x];
  for (int b = t; b < NBINS; b += 256) ncur[b] = nrunoff[b * nC + blockIdx.x];
  __syncthreads();
  const int base = blockIdx.x * CHUNK;
  int end = base + CHUNK; if (end > nnz) end = nnz;
  for (int i = base + t; i < end; i += 256) {
    int e = edge_idx[i];
    int n = node_idx[i];
    int p = atomicAdd(&ecur[e >> EBIN_SHIFT], 1);
    epairs[p] = make_int2(e, n);
    int q = atomicAdd(&ncur[n >> NBIN_SHIFT], 1);
    npairs[q] = make_int2(n, e);
  }
}

__global__ __launch_bounds__(256) void bin_scatter_kernel(
    const int2* __restrict__ epairs, const int2* __restrict__ npairs,
    const int* __restrict__ ebinbase, const int* __restrict__ nbinbase,
    int* __restrict__ eoff, int* __restrict__ noff,
    int* __restrict__ enbr, int* __restrict__ nnbr,
    int n_edges, int n_nodes) {
  __shared__ int cnt[256];
  __shared__ int scn[256];
  const int bid = blockIdx.x;
  const int t = threadIdx.x;
  if (bid < EBINS) {
    const int e0 = bid << EBIN_SHIFT;
    const int ne = min(1 << EBIN_SHIFT, n_edges - e0);
    const int beg = ebinbase[bid], end = ebinbase[bid + 1];
    if (t < 128) cnt[t] = 0;
    __syncthreads();
    for (int j = beg + t; j < end; j += 256) atomicAdd(&cnt[epairs[j].x & 127], 1);
    __syncthreads();
    if (t < 128) scn[t] = cnt[t];
    __syncthreads();
    for (int d = 1; d < 128; d <<= 1) {
      int x = 0;
      if (t < 128 && t >= d) x = scn[t - d];
      __syncthreads();
      if (t < 128) scn[t] += x;
      __syncthreads();
    }
    int pos0 = 0;
    if (t < 128) {
      int excl = (t > 0) ? scn[t - 1] : 0;
      pos0 = beg + excl;
      if (t < ne) eoff[e0 + t] = pos0;
    }
    __syncthreads();
    if (t < 128) scn[t] = pos0;
    __syncthreads();
    for (int j = beg + t; j < end; j += 256) {
      int2 p = epairs[j];
      int pos = atomicAdd(&scn[p.x & 127], 1);
      enbr[pos] = p.y;
    }
    if (bid == EBINS - 1 && t == 0) eoff[n_edges] = end;
  } else {
    const int b = bid - EBINS;
    const int n0 = b << NBIN_SHIFT;
    const int nn = min(1 << NBIN_SHIFT, n_nodes - n0);
    const int beg = nbinbase[b], end = nbinbase[b + 1];
    cnt[t] = 0;
    __syncthreads();
    for (int j = beg + t; j < end; j += 256) atomicAdd(&cnt[npairs[j].x & 255], 1);
    __syncthreads();
    scn[t] = cnt[t];
    __syncthreads();
    for (int d = 1; d < 256; d <<= 1) {
      int x = (t >= d) ? scn[t - d] : 0;
      __syncthreads();
      scn[t] += x;
      __syncthreads();
    }
    int excl = (t > 0) ? scn[t - 1] : 0;
    int pos0 = beg + excl;
    if (t < nn) noff[n0 + t] = pos0;
    __syncthreads();
    scn[t] = pos0;
    __syncthreads();
    for (int j = beg + t; j < end; j += 256) {
      int2 p = npairs[j];
      int pos = atomicAdd(&scn[p.x & 255], 1);
      nnbr[pos] = p.y;
    }
    if (bid == EBINS + NBINS - 1 && t == 0) noff[n_nodes] = end;
  }
}

// ---------------- W1 transpose+convert: W1t16[n][k] = fp16(W1[k][n]) ----------------

__global__ __launch_bounds__(256) void w1t_kernel(
    const float* __restrict__ W1, __half* __restrict__ W1t) {
  int i = blockIdx.x * 256 + threadIdx.x;   // 0..16383
  int n = i >> 7, k = i & 127;
  W1t[i] = __float2half(W1[k * 128 + n]);
}

// ---------------- GEMM1 (MFMA): xw16[M x 128] = fp16(x) @ fp16(W1) ----------------
// 256 thr = 4 waves; block tile 64(M) x 128(N); K=128 in 4 chunks of 32.
// LDS stride 136 halves (68 dwords -> 2-way bank aliasing only, free per m136).

__global__ __launch_bounds__(256) void gemm1_kernel(
    const float* __restrict__ A, const __half* __restrict__ W1t16,
    __half* __restrict__ C16, int M) {
  __shared__ _Float16 As[64 * 136];
  __shared__ _Float16 Bs[128 * 136];
  const int t = threadIdx.x;
  const int bm = blockIdx.x * 64;

  // stage A rows (fp32 -> fp16): 64x128 = 2048 float4 / 256 thr = 8 iters
#pragma unroll
  for (int i = 0; i < 8; ++i) {
    int lin = i * 256 + t;
    int row = lin >> 5;
    int c4 = lin & 31;
    int grow = bm + row;
    float4 v = make_float4(0.f, 0.f, 0.f, 0.f);
    if (grow < M) v = *(const float4*)(A + (size_t)grow * 128 + c4 * 4);
    _Float16* dst = &As[row * 136 + c4 * 4];
    dst[0] = (_Float16)v.x; dst[1] = (_Float16)v.y;
    dst[2] = (_Float16)v.z; dst[3] = (_Float16)v.w;
  }
  // stage Bs = W1t16 [n][k]: 128 rows x 16 chunks of 16B = 2048 / 256 = 8 iters
#pragma unroll
  for (int i = 0; i < 8; ++i) {
    int lin = i * 256 + t;
    int n = lin >> 4;
    int c = lin & 15;
    *(float4*)&Bs[n * 136 + c * 8] = *(const float4*)(W1t16 + n * 128 + c * 8);
  }
  __syncthreads();

  const int w = t >> 6;
  const int lane = t & 63;
  const int l16 = lane & 15;
  const int quad = lane >> 4;

  f32x4 acc[8];
#pragma unroll
  for (int n = 0; n < 8; ++n) acc[n] = (f32x4){0.f, 0.f, 0.f, 0.f};

  const _Float16* arow = &As[(w * 16 + l16) * 136 + quad * 8];
#pragma unroll
  for (int kt = 0; kt < 4; ++kt) {
    half8 a = *(const half8*)(arow + kt * 32);
#pragma unroll
    for (int n = 0; n < 8; ++n) {
      half8 b = *(const half8*)&Bs[(n * 16 + l16) * 136 + kt * 32 + quad * 8];
      acc[n] = __builtin_amdgcn_mfma_f32_16x16x32_f16(a, b, acc[n], 0, 0, 0);
    }
  }
  __syncthreads();   // all frag reads done; reuse As as C-staging

  // C/D layout (m89-verified, dtype-independent): col=lane&15, row=quad*4+reg
#pragma unroll
  for (int n = 0; n < 8; ++n) {
#pragma unroll
    for (int r = 0; r < 4; ++r) {
      int row = w * 16 + quad * 4 + r;
      int col = n * 16 + l16;
      As[row * 136 + col] = (_Float16)acc[n][r];
    }
  }
  __syncthreads();

  // coalesced store: 64 rows x 16 chunks of 16B = 1024 / 256 = 4 iters
#pragma unroll
  for (int i = 0; i < 4; ++i) {
    int lin = i * 256 + t;
    int row = lin >> 4;
    int c = lin & 15;
    int grow = bm + row;
    if (grow < M)
      *(float4*)(C16 + (size_t)grow * 128 + c * 8) = *(const float4*)&As[row * 136 + c * 8];
  }
}

// ---------------- F=128 aggregation: 4-row x 16-chunk dwordx4 gathers ----------------

__device__ __forceinline__ void acc_h8(float* ax, float4 v) {
  const __half2* h = (const __half2*)&v;
#pragma unroll
  for (int q = 0; q < 4; ++q) {
    float2 f = __half22float2(h[q]);
    ax[2 * q] += f.x; ax[2 * q + 1] += f.y;
  }
}

__global__ __launch_bounds__(256) void edge_agg128_kernel(
    const float4* __restrict__ feat,
    const int* __restrict__ nbr, const int* __restrict__ off,
    float4* __restrict__ outf, int nseg) {
  int w = (blockIdx.x * 256 + threadIdx.x) >> 6;
  if (w >= nseg) return;
  const int lane = threadIdx.x & 63;
  const int r = lane >> 4;
  const int f = lane & 15;
  int beg = off[w], end = off[w + 1];
  float ax[8];
#pragma unroll
  for (int i = 0; i < 8; ++i) ax[i] = 0.f;
  int k = beg + r;
  for (; k + 12 < end; k += 16) {
    int n0 = nbr[k], n1 = nbr[k + 4], n2 = nbr[k + 8], n3 = nbr[k + 12];
    float4 v0 = feat[(size_t)n0 * 16 + f];
    float4 v1 = feat[(size_t)n1 * 16 + f];
    float4 v2 = feat[(size_t)n2 * 16 + f];
    float4 v3 = feat[(size_t)n3 * 16 + f];
    acc_h8(ax, v0); acc_h8(ax, v1); acc_h8(ax, v2); acc_h8(ax, v3);
  }
  for (; k < end; k += 4) acc_h8(ax, feat[(size_t)nbr[k] * 16 + f]);
#pragma unroll
  for (int i = 0; i < 8; ++i) {
    ax[i] += __shfl_xor(ax[i], 16, 64);
    ax[i] += __shfl_xor(ax[i], 32, 64);
  }
  if (r == 0) {
    float inv = (end > beg) ? 1.f / (float)(end - beg) : 0.f;
    union { float4 f4; __half2 h[4]; } u;
#pragma unroll
    for (int q = 0; q < 4; ++q)
      u.h[q] = __floats2half2_rn(ax[2 * q] * inv, ax[2 * q + 1] * inv);
    outf[(size_t)w * 16 + f] = u.f4;
  }
}

__global__ __launch_bounds__(256) void node_agg128_kernel(
    const float4* __restrict__ feat,
    const int* __restrict__ nbr, const int* __restrict__ off,
    const float* __restrict__ bias,
    float4* __restrict__ outf, int nseg) {
  int w = (blockIdx.x * 256 + threadIdx.x) >> 6;
  if (w >= nseg) return;
  const int lane = threadIdx.x & 63;
  const int r = lane >> 4;
  const int f = lane & 15;
  int beg = off[w], end = off[w + 1];
  float ax[8];
#pragma unroll
  for (int i = 0; i < 8; ++i) ax[i] = 0.f;
  int k = beg + r;
  for (; k + 12 < end; k += 16) {
    int e0 = nbr[k], e1 = nbr[k + 4], e2 = nbr[k + 8], e3 = nbr[k + 12];
    float4 v0 = feat[(size_t)e0 * 16 + f];
    float4 v1 = feat[(size_t)e1 * 16 + f];
    float4 v2 = feat[(size_t)e2 * 16 + f];
    float4 v3 = feat[(size_t)e3 * 16 + f];
    acc_h8(ax, v0); acc_h8(ax, v1); acc_h8(ax, v2); acc_h8(ax, v3);
  }
  for (; k < end; k += 4) acc_h8(ax, feat[(size_t)nbr[k] * 16 + f]);
#pragma unroll
  for (int i = 0; i < 8; ++i) {
    ax[i] += __shfl_xor(ax[i], 16, 64);
    ax[i] += __shfl_xor(ax[i], 32, 64);
  }
  if (r == 0) {
    float inv = (end > beg) ? 1.f / (float)(end - beg) : 0.f;
    float4 blo = ((const float4*)bias)[2 * f];
    float4 bhi = ((const float4*)bias)[2 * f + 1];
    float bb[8] = {blo.x, blo.y, blo.z, blo.w, bhi.x, bhi.y, bhi.z, bhi.w};
    union { float4 f4; __half2 h[4]; } u;
#pragma unroll
    for (int q = 0; q < 4; ++q) {
      float hx = fmaxf(ax[2 * q] * inv + bb[2 * q], 0.f);
      float hy = fmaxf(ax[2 * q + 1] * inv + bb[2 * q + 1], 0.f);
      u.h[q] = __floats2half2_rn(hx, hy);
    }
    outf[(size_t)w * 16 + f] = u.f4;
  }
}

// ---------------- GEMM2: hw2_16[M x 16] (fp16) = h16[M x 128] @ W2[128 x 16] ----------

__global__ __launch_bounds__(256) void gemm2_kernel(
    const __half* __restrict__ H16, const float* __restrict__ W2,
    __half2* __restrict__ O16, int M) {
  __shared__ float ws2[128 * 16];
  const int t = threadIdx.x;
#pragma unroll
  for (int i = 0; i < 8; ++i) ws2[i * 256 + t] = W2[i * 256 + t];
  __syncthreads();

  int r0 = blockIdx.x * 512 + t;
  int r1 = r0 + 256;
  bool v0 = r0 < M, v1 = r1 < M;
  const __half2* h0 = (const __half2*)(H16 + (size_t)r0 * 128);
  const __half2* h1 = (const __half2*)(H16 + (size_t)r1 * 128);

  float4 acc0[4], acc1[4];
#pragma unroll
  for (int q = 0; q < 4; ++q) {
    acc0[q] = make_float4(0.f, 0.f, 0.f, 0.f);
    acc1[q] = make_float4(0.f, 0.f, 0.f, 0.f);
  }

  for (int k4 = 0; k4 < 32; ++k4) {
    float2 f00 = make_float2(0.f, 0.f), f01 = make_float2(0.f, 0.f);
    float2 f10 = make_float2(0.f, 0.f), f11 = make_float2(0.f, 0.f);
    if (v0) { f00 = __half22float2(h0[2 * k4]); f01 = __half22float2(h0[2 * k4 + 1]); }
    if (v1) { f10 = __half22float2(h1[2 * k4]); f11 = __half22float2(h1[2 * k4 + 1]); }
    const float a0s[4] = {f00.x, f00.y, f01.x, f01.y};
    const float a1s[4] = {f10.x, f10.y, f11.x, f11.y};
#pragma unroll
    for (int j = 0; j < 4; ++j) {
      int k = k4 * 4 + j;
#pragma unroll
      for (int q = 0; q < 4; ++q) {
        float4 b = *(const float4*)&ws2[k * 16 + q * 4];
        acc0[q].x = fmaf(a0s[j], b.x, acc0[q].x);
        acc0[q].y = fmaf(a0s[j], b.y, acc0[q].y);
        acc0[q].z = fmaf(a0s[j], b.z, acc0[q].z);
        acc0[q].w = fmaf(a0s[j], b.w, acc0[q].w);
        acc1[q].x = fmaf(a1s[j], b.x, acc1[q].x);
        acc1[q].y = fmaf(a1s[j], b.y, acc1[q].y);
        acc1[q].z = fmaf(a1s[j], b.z, acc1[q].z);
        acc1[q].w = fmaf(a1s[j], b.w, acc1[q].w);
      }
    }
  }
  if (v0) {
    __half2* op = O16 + (size_t)r0 * 8;
#pragma unroll
    for (int q = 0; q < 4; ++q) {
      op[q * 2]     = __floats2half2_rn(acc0[q].x, acc0[q].y);
      op[q * 2 + 1] = __floats2half2_rn(acc0[q].z, acc0[q].w);
    }
  }
  if (v1) {
    __half2* op = O16 + (size_t)r1 * 8;
#pragma unroll
    for (int q = 0; q < 4; ++q) {
      op[q * 2]     = __floats2half2_rn(acc1[q].x, acc1[q].y);
      op[q * 2 + 1] = __floats2half2_rn(acc1[q].z, acc1[q].w);
    }
  }
}

// ---------------- F=16 aggregation ----------------

__global__ __launch_bounds__(256) void edge_agg16_kernel(
    const __half* __restrict__ feat, const int* __restrict__ nbr,
    const int* __restrict__ off, float* __restrict__ outf, int nseg) {
  int gid = blockIdx.x * 256 + threadIdx.x;
  int seg = gid >> 4;
  int c = gid & 15;
  if (seg >= nseg) return;
  int beg = off[seg], end = off[seg + 1];
  float a0 = 0.f, a1 = 0.f, a2 = 0.f, a3 = 0.f;
  int j = beg;
  for (; j + 8 <= end; j += 8) {
    int n0 = nbr[j],     n1 = nbr[j + 1], n2 = nbr[j + 2], n3 = nbr[j + 3];
    int n4 = nbr[j + 4], n5 = nbr[j + 5], n6 = nbr[j + 6], n7 = nbr[j + 7];
    float v0 = __half2float(feat[(size_t)n0 * 16 + c]);
    float v1 = __half2float(feat[(size_t)n1 * 16 + c]);
    float v2 = __half2float(feat[(size_t)n2 * 16 + c]);
    float v3 = __half2float(feat[(size_t)n3 * 16 + c]);
    float v4 = __half2float(feat[(size_t)n4 * 16 + c]);
    float v5 = __half2float(feat[(size_t)n5 * 16 + c]);
    float v6 = __half2float(feat[(size_t)n6 * 16 + c]);
    float v7 = __half2float(feat[(size_t)n7 * 16 + c]);
    a0 += v0 + v4; a1 += v1 + v5; a2 += v2 + v6; a3 += v3 + v7;
  }
  for (; j < end; ++j) a0 += __half2float(feat[(size_t)nbr[j] * 16 + c]);
  float inv = (end > beg) ? 1.f / (float)(end - beg) : 0.f;
  outf[(size_t)seg * 16 + c] = ((a0 + a1) + (a2 + a3)) * inv;
}

__global__ __launch_bounds__(256) void node_agg16_kernel(
    const float* __restrict__ feat, const int* __restrict__ nbr,
    const int* __restrict__ off, const float* __restrict__ bias,
    float* __restrict__ outf, int nseg) {
  int gid = blockIdx.x * 256 + threadIdx.x;
  int seg = gid >> 4;
  int c = gid & 15;
  if (seg >= nseg) return;
  int beg = off[seg], end = off[seg + 1];
  float a0 = 0.f, a1 = 0.f, a2 = 0.f, a3 = 0.f;
  int j = beg;
  for (; j + 8 <= end; j += 8) {
    int n0 = nbr[j],     n1 = nbr[j + 1], n2 = nbr[j + 2], n3 = nbr[j + 3];
    int n4 = nbr[j + 4], n5 = nbr[j + 5], n6 = nbr[j + 6], n7 = nbr[j + 7];
    float v0 = feat[(size_t)n0 * 16 + c];
    float v1 = feat[(size_t)n1 * 16 + c];
    float v2 = feat[(size_t)n2 * 16 + c];
    float v3 = feat[(size_t)n3 * 16 + c];
    float v4 = feat[(size_t)n4 * 16 + c];
    float v5 = feat[(size_t)n5 * 16 + c];
    float v6 = feat[(size_t)n6 * 16 + c];
    float v7 = feat[(size_t)n7 * 16 + c];
    a0 += v0 + v4; a1 += v1 + v5; a2 += v2 + v6; a3 += v3 + v7;
  }
  for (; j < end; ++j) a0 += feat[(size_t)nbr[j] * 16 + c];
  float inv = (end > beg) ? 1.f / (float)(end - beg) : 0.f;
  outf[(size_t)seg * 16 + c] = ((a0 + a1) + (a2 + a3)) * inv + bias[c];
}

// ---------------- launch ----------------

extern "C" void kernel_launch(void* const* d_in, const int* in_sizes, int n_in,
                              void* d_out, int out_size, void* d_ws, size_t ws_size,
                              hipStream_t stream) {
  const float* x        = (const float*)d_in[0];
  const int*   node_idx = (const int*)d_in[1];
  const int*   edge_idx = (const int*)d_in[2];
  const float* W1 = (const float*)d_in[4];
  const float* b1 = (const float*)d_in[5];
  const float* W2 = (const float*)d_in[6];
  const float* b2 = (const float*)d_in[7];
  float* out = (float*)d_out;

  const int n_nodes = in_sizes[0] / F1;  // 100000
  const int nnz     = in_sizes[1];       // 1600000
  const int n_edges = N_EDGES_C;         // 50000
  const int nC      = (nnz + CHUNK - 1) / CHUNK;   // 391
  const int Le      = EBINS * nC;
  const int Ln      = NBINS * nC;
  const int nbE     = (Le + 1023) / 1024;
  const int nbN     = (Ln + 1023) / 1024;

  char* ws = (char*)d_ws;
  int2*    epairs = (int2*)(ws + 0);            // 12.8M transient
  int2*    npairs = (int2*)(ws + 12800000);     // 12.8M transient
  __half*  h16    = (__half*)(ws + 0);          // 25.6M flat (after bin_scatter)
  __half*  xw16   = (__half*)(ws + 25600000);   // 25.6M flat
  __half*  ef16   = (__half*)(ws + 51200000);   // 12.8M flat
  __half*  hw216  = (__half*)(ws + 64000000);   //  3.2M fp16
  float*   ef2    = (float*)(ws + 70400000);    //  3.2M
  int*     enbr   = (int*)(ws + 73600000);      //  6.4M
  int*     nnbr   = (int*)(ws + 80000000);      //  6.4M
  int*     eoff   = (int*)(ws + 86400000);
  int*     noff   = (int*)(ws + 86600008);
  int*     echunkcnt = (int*)(ws + 87000016);
  int*     nchunkcnt = (int*)(ws + 87611540);
  int*     erunoff   = (int*)(ws + 88223064);
  int*     nrunoff   = (int*)(ws + 88834588);
  int*     ebinbase  = (int*)(ws + 89446112);
  int*     nbinbase  = (int*)(ws + 89447680);
  int*     epart     = (int*)(ws + 89449248);
  int*     npart     = (int*)(ws + 89450272);
  __half*  w1t16     = (__half*)(ws + 89451520); // 32,768 -> end 89,484,288

  w1t_kernel<<<64, 256, 0, stream>>>(W1, w1t16);

  hist_chunk_kernel<<<nC, 256, 0, stream>>>(node_idx, edge_idx,
                                            echunkcnt, nchunkcnt, nnz);
  cscan_p1_kernel<<<nbE + nbN, 256, 0, stream>>>(echunkcnt, nchunkcnt,
                                                 epart, npart, Le, Ln, nbE);
  cscan_p2_kernel<<<1, 256, 0, stream>>>(epart, npart, ebinbase, nbinbase,
                                         nbE, nbN, nnz);
  cscan_p3_kernel<<<nbE + nbN, 256, 0, stream>>>(echunkcnt, nchunkcnt,
                                                 epart, npart, erunoff, nrunoff,
                                                 ebinbase, nbinbase, Le, Ln, nbE, nC);
  stage_kernel<<<nC, 256, 0, stream>>>(node_idx, edge_idx, erunoff, nrunoff,
                                       epairs, npairs, nnz);
  bin_scatter_kernel<<<EBINS + NBINS, 256, 0, stream>>>(epairs, npairs,
                                                        ebinbase, nbinbase,
                                                        eoff, noff, enbr, nnbr,
                                                        n_edges, n_nodes);

  // layer 1 (fp16 flat message path)
  gemm1_kernel<<<(n_nodes + 63) / 64, 256, 0, stream>>>(x, w1t16, xw16, n_nodes);
  edge_agg128_kernel<<<(n_edges * 64 + 255) / 256, 256, 0, stream>>>(
      (const float4*)xw16, enbr, eoff, (float4*)ef16, n_edges);
  node_agg128_kernel<<<(n_nodes * 64 + 255) / 256, 256, 0, stream>>>(
      (const float4*)ef16, nnbr, noff, b1, (float4*)h16, n_nodes);

  // layer 2
  gemm2_kernel<<<(n_nodes + 511) / 512, 256, 0, stream>>>(h16, W2,
                                                          (__half2*)hw216, n_nodes);
  edge_agg16_kernel<<<(n_edges * 16 + 255) / 256, 256, 0, stream>>>(
      hw216, enbr, eoff, ef2, n_edges);
  node_agg16_kernel<<<(n_nodes * 16 + 255) / 256, 256, 0, stream>>>(
      ef2, nnbr, noff, b2, out, n_nodes);
}